// Round 2
// baseline (28.642 us; speedup 1.0000x reference)
//
#include <hip/hip_runtime.h>
#include <math.h>

// QNN forward: logits[b,c] = fc_b[c] + (sum_j wv[c][j] * |psi_j|^2) / ||x_b||^2
// psi = (U0 (x) U1 (x) U2 (x) U3) @ x_b   (CNOT row-permutation folded into wv)
//
// ws layout (floats):
//   [0..31]  gates: qubit q at ws+8q: {g00r,g00i,g01r,g01i,g10r,g10i,g11r,g11i}
//   [32..79] wv[3][16] (CNOT-permuted Z/fc_w contraction weights)
//   [80..82] fc_b

#define QNN_BATCH 1048576

__device__ __forceinline__ int qnn_cnot_perm(int k, int c, int t) {
    int cbit = 1 << (3 - c), tbit = 1 << (3 - t);
    return (k & cbit) ? (k ^ tbit) : k;
}

__global__ void qnn_setup(const float* __restrict__ params,
                          const float* __restrict__ fc_w,
                          const float* __restrict__ fc_b,
                          float* __restrict__ ws) {
    if (threadIdx.x != 0 || blockIdx.x != 0) return;
    // Per-qubit gate Ui = RZ @ RY @ RX
    for (int q = 0; q < 4; ++q) {
        float hx = 0.5f * params[q * 3 + 0];
        float hy = 0.5f * params[q * 3 + 1];
        float hz = 0.5f * params[q * 3 + 2];
        float cx = cosf(hx), sx = sinf(hx);
        float cy = cosf(hy), sy = sinf(hy);
        float cz = cosf(hz), sz = sinf(hz);
        float A = cy * cx, B = sy * sx, C = sy * cx, D = cy * sx;
        float* g = ws + q * 8;
        g[0] =  cz * A + sz * B;   // g00 re
        g[1] =  cz * B - sz * A;   // g00 im
        g[2] = -cz * C - sz * D;   // g01 re
        g[3] =  sz * C - cz * D;   // g01 im
        g[4] =  cz * C + sz * D;   // g10 re
        g[5] =  sz * C - cz * D;   // g10 im
        g[6] =  cz * A + sz * B;   // g11 re
        g[7] =  sz * A - cz * B;   // g11 im
    }
    // wv[c][q(o)] = sum_w fc_w[c,w] * zsign(o,w);  q = p01 o p12 o p23
    for (int o = 0; o < 16; ++o) {
        int j = qnn_cnot_perm(qnn_cnot_perm(qnn_cnot_perm(o, 2, 3), 1, 2), 0, 1);
        for (int c = 0; c < 3; ++c) {
            float s = 0.f;
            for (int w = 0; w < 4; ++w) {
                float z = 1.f - 2.f * (float)((o >> (3 - w)) & 1);
                s += fc_w[c * 4 + w] * z;
            }
            ws[32 + c * 16 + j] = s;
        }
    }
    for (int c = 0; c < 3; ++c) ws[80 + c] = fc_b[c];
}

// Complex butterfly stage with stride S (gate at G), in-place on yr/yi.
#define QNN_CSTAGE(S, G)                                                        \
    do {                                                                        \
        const float g00r=(G)[0], g00i=(G)[1], g01r=(G)[2], g01i=(G)[3];         \
        const float g10r=(G)[4], g10i=(G)[5], g11r=(G)[6], g11i=(G)[7];         \
        _Pragma("unroll")                                                       \
        for (int base = 0; base < 16; base += 2 * (S)) {                        \
            _Pragma("unroll")                                                   \
            for (int k = 0; k < (S); ++k) {                                     \
                const int j0 = base + k, j1 = j0 + (S);                         \
                const float ar = yr[j0], ai = yi[j0];                           \
                const float br = yr[j1], bi = yi[j1];                           \
                yr[j0] = fmaf(g00r, ar, fmaf(-g00i, ai, fmaf(g01r, br, -g01i * bi))); \
                yi[j0] = fmaf(g00r, ai, fmaf( g00i, ar, fmaf(g01r, bi,  g01i * br))); \
                yr[j1] = fmaf(g10r, ar, fmaf(-g10i, ai, fmaf(g11r, br, -g11i * bi))); \
                yi[j1] = fmaf(g10r, ai, fmaf( g10i, ar, fmaf(g11r, bi,  g11i * br))); \
            }                                                                   \
        }                                                                       \
    } while (0)

__global__ __launch_bounds__(256) void qnn_main(const float* __restrict__ x,
                                                const float* __restrict__ ws,
                                                float* __restrict__ out) {
    // Per-wave LDS transpose staging: rows padded to 20 floats (80 B) so
    // ds_read_b128/ds_write_b128 stay 16B-aligned and lanes spread across all
    // eight 4-bank groups (~4-way effective conflict, 1.58x — cheap).
    __shared__ float lds[4][64][20];

    const int lane = threadIdx.x & 63;
    const int w    = threadIdx.x >> 6;
    const long long wb = (long long)(blockIdx.x * 4 + w) * 64;  // wave's first sample

    // Lane-contiguous coalesced loads of this wave's 64 samples (4 KB):
    // float4 #n of the chunk -> sample n>>2, group n&3.
    const float4* xs = (const float4*)(x + wb * 16);
#pragma unroll
    for (int k = 0; k < 4; ++k) {
        const int n = k * 64 + lane;
        const float4 v = xs[n];
        *(float4*)&lds[w][n >> 2][(n & 3) * 4] = v;
    }
    __syncthreads();

    float xv[16];
#pragma unroll
    for (int g = 0; g < 4; ++g) {
        const float4 v = *(const float4*)&lds[w][lane][g * 4];
        xv[g * 4 + 0] = v.x; xv[g * 4 + 1] = v.y;
        xv[g * 4 + 2] = v.z; xv[g * 4 + 3] = v.w;
    }

    float n2 = 0.f;
#pragma unroll
    for (int i = 0; i < 16; ++i) n2 = fmaf(xv[i], xv[i], n2);

    float yr[16], yi[16];
    // Stage qubit 0 (stride 8), real input.
    {
        const float g00r = ws[0], g00i = ws[1], g01r = ws[2], g01i = ws[3];
        const float g10r = ws[4], g10i = ws[5], g11r = ws[6], g11i = ws[7];
#pragma unroll
        for (int k = 0; k < 8; ++k) {
            const float a = xv[k], b = xv[k + 8];
            yr[k]     = fmaf(g00r, a, g01r * b);
            yi[k]     = fmaf(g00i, a, g01i * b);
            yr[k + 8] = fmaf(g10r, a, g11r * b);
            yi[k + 8] = fmaf(g10i, a, g11i * b);
        }
    }
    QNN_CSTAGE(4, ws + 8);   // qubit 1
    QNN_CSTAGE(2, ws + 16);  // qubit 2
    QNN_CSTAGE(1, ws + 24);  // qubit 3

    float acc0 = 0.f, acc1 = 0.f, acc2 = 0.f;
#pragma unroll
    for (int j = 0; j < 16; ++j) {
        const float p = fmaf(yr[j], yr[j], yi[j] * yi[j]);
        acc0 = fmaf(ws[32 + j], p, acc0);
        acc1 = fmaf(ws[48 + j], p, acc1);
        acc2 = fmaf(ws[64 + j], p, acc2);
    }
    const float inv = 1.0f / n2;
    float* o = out + (wb + lane) * 3;
    o[0] = fmaf(acc0, inv, ws[80]);
    o[1] = fmaf(acc1, inv, ws[81]);
    o[2] = fmaf(acc2, inv, ws[82]);
}

extern "C" void kernel_launch(void* const* d_in, const int* in_sizes, int n_in,
                              void* d_out, int out_size, void* d_ws, size_t ws_size,
                              hipStream_t stream) {
    (void)in_sizes; (void)n_in; (void)out_size; (void)ws_size;
    const float* x      = (const float*)d_in[0];
    const float* params = (const float*)d_in[1];
    const float* fc_w   = (const float*)d_in[2];
    const float* fc_b   = (const float*)d_in[3];
    float* ws  = (float*)d_ws;
    float* out = (float*)d_out;

    qnn_setup<<<1, 64, 0, stream>>>(params, fc_w, fc_b, ws);
    qnn_main<<<QNN_BATCH / 256, 256, 0, stream>>>(x, ws, out);
}

// Round 3
// 28.343 us; speedup vs baseline: 1.0106x; 1.0106x over previous
//
#include <hip/hip_runtime.h>
#include <math.h>

// QNN forward, single fused kernel:
//   logits[b,c] = fc_b[c] + (sum_j wv[c][j] * |psi_j|^2) / ||x_b||^2
//   psi = (U0 (x) U1 (x) U2 (x) U3) @ x_b   (CNOT row-perm folded into wv)
//
// Per-block: thread 0 recomputes the 83 shared constants into LDS while the
// block's x-loads are in flight (hides under HBM latency); everyone reads
// them via same-address LDS broadcast after the staging barrier.
//
// cons layout (floats):
//   [0..31]  gates: qubit q at 8q: {g00r,g00i,g01r,g01i,g10r,g10i,g11r,g11i}
//   [32..79] wv[3][16] (CNOT-permuted Z/fc_w contraction weights)
//   [80..82] fc_b

#define QNN_BATCH 1048576

__device__ __forceinline__ int qnn_cnot_perm(int k, int c, int t) {
    int cbit = 1 << (3 - c), tbit = 1 << (3 - t);
    return (k & cbit) ? (k ^ tbit) : k;
}

// Complex butterfly stage with stride S (gate at G), in-place on yr/yi.
#define QNN_CSTAGE(S, G)                                                        \
    do {                                                                        \
        const float g00r=(G)[0], g00i=(G)[1], g01r=(G)[2], g01i=(G)[3];         \
        const float g10r=(G)[4], g10i=(G)[5], g11r=(G)[6], g11i=(G)[7];         \
        _Pragma("unroll")                                                       \
        for (int base = 0; base < 16; base += 2 * (S)) {                        \
            _Pragma("unroll")                                                   \
            for (int k = 0; k < (S); ++k) {                                     \
                const int j0 = base + k, j1 = j0 + (S);                         \
                const float ar = yr[j0], ai = yi[j0];                           \
                const float br = yr[j1], bi = yi[j1];                           \
                yr[j0] = fmaf(g00r, ar, fmaf(-g00i, ai, fmaf(g01r, br, -g01i * bi))); \
                yi[j0] = fmaf(g00r, ai, fmaf( g00i, ar, fmaf(g01r, bi,  g01i * br))); \
                yr[j1] = fmaf(g10r, ar, fmaf(-g10i, ai, fmaf(g11r, br, -g11i * bi))); \
                yi[j1] = fmaf(g10r, ai, fmaf( g10i, ar, fmaf(g11r, bi,  g11i * br))); \
            }                                                                   \
        }                                                                       \
    } while (0)

__global__ __launch_bounds__(256) void qnn_fused(const float* __restrict__ x,
                                                 const float* __restrict__ params,
                                                 const float* __restrict__ fc_w,
                                                 const float* __restrict__ fc_b,
                                                 float* __restrict__ out) {
    __shared__ float cons[84];
    // Rows padded to 20 floats (80 B): ds_*_b128 stays 16B-aligned, lanes
    // spread across bank groups (~4-way conflict, cheap).
    __shared__ float lds[4][64][20];

    const int lane = threadIdx.x & 63;
    const int w    = threadIdx.x >> 6;
    const long long wb = (long long)(blockIdx.x * 4 + w) * 64;  // wave's first sample

    // Issue this wave's 64-sample (4 KB) coalesced loads first.
    const float4* xs = (const float4*)(x + wb * 16);
    float4 v[4];
#pragma unroll
    for (int k = 0; k < 4; ++k) v[k] = xs[k * 64 + lane];

    // Thread 0 computes the shared constants while loads are in flight.
    if (threadIdx.x == 0) {
        for (int q = 0; q < 4; ++q) {
            float hx = 0.5f * params[q * 3 + 0];
            float hy = 0.5f * params[q * 3 + 1];
            float hz = 0.5f * params[q * 3 + 2];
            float cx = cosf(hx), sx = sinf(hx);
            float cy = cosf(hy), sy = sinf(hy);
            float cz = cosf(hz), sz = sinf(hz);
            float A = cy * cx, B = sy * sx, C = sy * cx, D = cy * sx;
            float* g = cons + q * 8;
            g[0] =  cz * A + sz * B;   // g00 re
            g[1] =  cz * B - sz * A;   // g00 im
            g[2] = -cz * C - sz * D;   // g01 re
            g[3] =  sz * C - cz * D;   // g01 im
            g[4] =  cz * C + sz * D;   // g10 re
            g[5] =  sz * C - cz * D;   // g10 im
            g[6] =  cz * A + sz * B;   // g11 re
            g[7] =  sz * A - cz * B;   // g11 im
        }
        // wv[c][q(o)] = sum_w fc_w[c,w] * zsign(o,w);  q = p01 o p12 o p23
        for (int o = 0; o < 16; ++o) {
            int j = qnn_cnot_perm(qnn_cnot_perm(qnn_cnot_perm(o, 2, 3), 1, 2), 0, 1);
            for (int c = 0; c < 3; ++c) {
                float s = 0.f;
                for (int ww = 0; ww < 4; ++ww) {
                    float z = 1.f - 2.f * (float)((o >> (3 - ww)) & 1);
                    s += fc_w[c * 4 + ww] * z;
                }
                cons[32 + c * 16 + j] = s;
            }
        }
        for (int c = 0; c < 3; ++c) cons[80 + c] = fc_b[c];
    }

    // Stage x into LDS (transpose to per-thread rows).
#pragma unroll
    for (int k = 0; k < 4; ++k) {
        const int n = k * 64 + lane;
        *(float4*)&lds[w][n >> 2][(n & 3) * 4] = v[k];
    }
    __syncthreads();

    float xv[16];
#pragma unroll
    for (int g = 0; g < 4; ++g) {
        const float4 t = *(const float4*)&lds[w][lane][g * 4];
        xv[g * 4 + 0] = t.x; xv[g * 4 + 1] = t.y;
        xv[g * 4 + 2] = t.z; xv[g * 4 + 3] = t.w;
    }

    float n2 = 0.f;
#pragma unroll
    for (int i = 0; i < 16; ++i) n2 = fmaf(xv[i], xv[i], n2);

    float yr[16], yi[16];
    // Stage qubit 0 (stride 8), real input.
    {
        const float g00r = cons[0], g00i = cons[1], g01r = cons[2], g01i = cons[3];
        const float g10r = cons[4], g10i = cons[5], g11r = cons[6], g11i = cons[7];
#pragma unroll
        for (int k = 0; k < 8; ++k) {
            const float a = xv[k], b = xv[k + 8];
            yr[k]     = fmaf(g00r, a, g01r * b);
            yi[k]     = fmaf(g00i, a, g01i * b);
            yr[k + 8] = fmaf(g10r, a, g11r * b);
            yi[k + 8] = fmaf(g10i, a, g11i * b);
        }
    }
    QNN_CSTAGE(4, cons + 8);   // qubit 1
    QNN_CSTAGE(2, cons + 16);  // qubit 2
    QNN_CSTAGE(1, cons + 24);  // qubit 3

    float acc0 = 0.f, acc1 = 0.f, acc2 = 0.f;
#pragma unroll
    for (int j = 0; j < 16; ++j) {
        const float p = fmaf(yr[j], yr[j], yi[j] * yi[j]);
        acc0 = fmaf(cons[32 + j], p, acc0);
        acc1 = fmaf(cons[48 + j], p, acc1);
        acc2 = fmaf(cons[64 + j], p, acc2);
    }
    const float inv = 1.0f / n2;
    float* o = out + (wb + lane) * 3;
    o[0] = fmaf(acc0, inv, cons[80]);
    o[1] = fmaf(acc1, inv, cons[81]);
    o[2] = fmaf(acc2, inv, cons[82]);
}

extern "C" void kernel_launch(void* const* d_in, const int* in_sizes, int n_in,
                              void* d_out, int out_size, void* d_ws, size_t ws_size,
                              hipStream_t stream) {
    (void)in_sizes; (void)n_in; (void)out_size; (void)d_ws; (void)ws_size;
    const float* x      = (const float*)d_in[0];
    const float* params = (const float*)d_in[1];
    const float* fc_w   = (const float*)d_in[2];
    const float* fc_b   = (const float*)d_in[3];
    float* out = (float*)d_out;

    qnn_fused<<<QNN_BATCH / 256, 256, 0, stream>>>(x, params, fc_w, fc_b, out);
}

// Round 4
// 27.094 us; speedup vs baseline: 1.0571x; 1.0461x over previous
//
#include <hip/hip_runtime.h>
#include <math.h>

// QNN forward, single fused kernel, 2 samples/thread:
//   logits[b,c] = fc_b[c] + (sum_j wv[c][j] * |psi_j|^2) / ||x_b||^2
//   psi = (U0 (x) U1 (x) U2 (x) U3) @ x_b   (CNOT row-perm folded into wv)
//
// cons layout (floats):
//   [0..31]  gates: qubit q at 8q: {g00r,g00i,g01r,g01i,g10r,g10i,g11r,g11i}
//   [32..79] wv[3][16] (CNOT-permuted Z/fc_w contraction weights)
//   [80..82] fc_b

#define QNN_BATCH 1048576

__device__ __forceinline__ int qnn_cnot_perm(int k, int c, int t) {
    int cbit = 1 << (3 - c), tbit = 1 << (3 - t);
    return (k & cbit) ? (k ^ tbit) : k;
}

// Complex butterfly stage with stride S (gate at G), in-place on yr/yi.
#define QNN_CSTAGE(S, G)                                                        \
    do {                                                                        \
        const float g00r=(G)[0], g00i=(G)[1], g01r=(G)[2], g01i=(G)[3];         \
        const float g10r=(G)[4], g10i=(G)[5], g11r=(G)[6], g11i=(G)[7];         \
        _Pragma("unroll")                                                       \
        for (int base = 0; base < 16; base += 2 * (S)) {                        \
            _Pragma("unroll")                                                   \
            for (int k = 0; k < (S); ++k) {                                     \
                const int j0 = base + k, j1 = j0 + (S);                         \
                const float ar = yr[j0], ai = yi[j0];                           \
                const float br = yr[j1], bi = yi[j1];                           \
                yr[j0] = fmaf(g00r, ar, fmaf(-g00i, ai, fmaf(g01r, br, -g01i * bi))); \
                yi[j0] = fmaf(g00r, ai, fmaf( g00i, ar, fmaf(g01r, bi,  g01i * br))); \
                yr[j1] = fmaf(g10r, ar, fmaf(-g10i, ai, fmaf(g11r, br, -g11i * bi))); \
                yi[j1] = fmaf(g10r, ai, fmaf( g10i, ar, fmaf(g11r, bi,  g11i * br))); \
            }                                                                   \
        }                                                                       \
    } while (0)

__device__ __forceinline__ void qnn_one(const float xv[16], const float* cons,
                                        float* l0, float* l1, float* l2) {
    float n2 = 0.f;
#pragma unroll
    for (int i = 0; i < 16; ++i) n2 = fmaf(xv[i], xv[i], n2);

    float yr[16], yi[16];
    // Stage qubit 0 (stride 8), real input.
    {
        const float g00r = cons[0], g00i = cons[1], g01r = cons[2], g01i = cons[3];
        const float g10r = cons[4], g10i = cons[5], g11r = cons[6], g11i = cons[7];
#pragma unroll
        for (int k = 0; k < 8; ++k) {
            const float a = xv[k], b = xv[k + 8];
            yr[k]     = fmaf(g00r, a, g01r * b);
            yi[k]     = fmaf(g00i, a, g01i * b);
            yr[k + 8] = fmaf(g10r, a, g11r * b);
            yi[k + 8] = fmaf(g10i, a, g11i * b);
        }
    }
    QNN_CSTAGE(4, cons + 8);   // qubit 1
    QNN_CSTAGE(2, cons + 16);  // qubit 2
    QNN_CSTAGE(1, cons + 24);  // qubit 3

    float acc0 = 0.f, acc1 = 0.f, acc2 = 0.f;
#pragma unroll
    for (int j = 0; j < 16; ++j) {
        const float p = fmaf(yr[j], yr[j], yi[j] * yi[j]);
        acc0 = fmaf(cons[32 + j], p, acc0);
        acc1 = fmaf(cons[48 + j], p, acc1);
        acc2 = fmaf(cons[64 + j], p, acc2);
    }
    const float inv = 1.0f / n2;
    *l0 = fmaf(acc0, inv, cons[80]);
    *l1 = fmaf(acc1, inv, cons[81]);
    *l2 = fmaf(acc2, inv, cons[82]);
}

__global__ __launch_bounds__(256) void qnn_fused(const float* __restrict__ x,
                                                 const float* __restrict__ params,
                                                 const float* __restrict__ fc_w,
                                                 const float* __restrict__ fc_b,
                                                 float* __restrict__ out) {
    __shared__ float cons[84];

    const int t = blockIdx.x * 256 + threadIdx.x;
    const size_t s0 = (size_t)t * 2;  // two consecutive samples per thread

    // Issue ALL global loads up front (8 x dwordx4, 128 B/thread, dense).
    const float4* xp = (const float4*)(x + s0 * 16);
    float4 v[8];
#pragma unroll
    for (int k = 0; k < 8; ++k) v[k] = xp[k];

    // Thread 0 computes shared constants while loads are in flight.
    if (threadIdx.x == 0) {
        for (int q = 0; q < 4; ++q) {
            float hx = 0.5f * params[q * 3 + 0];
            float hy = 0.5f * params[q * 3 + 1];
            float hz = 0.5f * params[q * 3 + 2];
            float cx = cosf(hx), sx = sinf(hx);
            float cy = cosf(hy), sy = sinf(hy);
            float cz = cosf(hz), sz = sinf(hz);
            float A = cy * cx, B = sy * sx, C = sy * cx, D = cy * sx;
            float* g = cons + q * 8;
            g[0] =  cz * A + sz * B;   // g00 re
            g[1] =  cz * B - sz * A;   // g00 im
            g[2] = -cz * C - sz * D;   // g01 re
            g[3] =  sz * C - cz * D;   // g01 im
            g[4] =  cz * C + sz * D;   // g10 re
            g[5] =  sz * C - cz * D;   // g10 im
            g[6] =  cz * A + sz * B;   // g11 re
            g[7] =  sz * A - cz * B;   // g11 im
        }
        // wv[c][q(o)] = sum_w fc_w[c,w] * zsign(o,w);  q = p01 o p12 o p23
        for (int o = 0; o < 16; ++o) {
            int j = qnn_cnot_perm(qnn_cnot_perm(qnn_cnot_perm(o, 2, 3), 1, 2), 0, 1);
            for (int c = 0; c < 3; ++c) {
                float s = 0.f;
                for (int ww = 0; ww < 4; ++ww) {
                    float z = 1.f - 2.f * (float)((o >> (3 - ww)) & 1);
                    s += fc_w[c * 4 + ww] * z;
                }
                cons[32 + c * 16 + j] = s;
            }
        }
        for (int c = 0; c < 3; ++c) cons[80 + c] = fc_b[c];
    }
    __syncthreads();

    float xa[16], xb[16];
#pragma unroll
    for (int k = 0; k < 4; ++k) {
        xa[k * 4 + 0] = v[k].x;     xa[k * 4 + 1] = v[k].y;
        xa[k * 4 + 2] = v[k].z;     xa[k * 4 + 3] = v[k].w;
        xb[k * 4 + 0] = v[k + 4].x; xb[k * 4 + 1] = v[k + 4].y;
        xb[k * 4 + 2] = v[k + 4].z; xb[k * 4 + 3] = v[k + 4].w;
    }

    float a0, a1, a2, b0, b1, b2;
    qnn_one(xa, cons, &a0, &a1, &a2);
    qnn_one(xb, cons, &b0, &b1, &b2);

    // 6 contiguous floats per thread; 24 B offset keeps float2 alignment.
    float2* o = (float2*)(out + s0 * 3);
    o[0] = make_float2(a0, a1);
    o[1] = make_float2(a2, b0);
    o[2] = make_float2(b1, b2);
}

extern "C" void kernel_launch(void* const* d_in, const int* in_sizes, int n_in,
                              void* d_out, int out_size, void* d_ws, size_t ws_size,
                              hipStream_t stream) {
    (void)in_sizes; (void)n_in; (void)out_size; (void)d_ws; (void)ws_size;
    const float* x      = (const float*)d_in[0];
    const float* params = (const float*)d_in[1];
    const float* fc_w   = (const float*)d_in[2];
    const float* fc_b   = (const float*)d_in[3];
    float* out = (float*)d_out;

    qnn_fused<<<QNN_BATCH / 512, 256, 0, stream>>>(x, params, fc_w, fc_b, out);
}